// Round 10
// baseline (71.638 us; speedup 1.0000x reference)
//
#include <hip/hip_runtime.h>
#include <math.h>

// GCDD fused v10: zero-LDS register sweep, HB=8 (2x TLP) + maskless interior
// + 6-column fixup kernel.
// out = u + div( phi(G)*ux, phi(G)*uy ); 3x3 Sobel cross-correlations with zero
// padding at EVERY conv stage (intermediates forced to 0 outside the domain).
//
// R9 post-mortem: latency-stall-bound at 3 waves/SIMD (grid-limited TLP); ILP
// fixes (R8 depth-4, R9 prefetch) don't substitute. Threads are independent ->
// tile height is a free TLP knob: HB=8 doubles waves/SIMD to 6 (ops x1.27 from
// vertical halo). Column masks dropped entirely: unmasked cascade is wrong only
// at out cols {0,1,2,W-3,W-2,W-1} (clamped-load garbage propagates <=3 cols);
// gcdd_fix rewrites those 6 columns with the fully-masked per-pixel cascade.
//
// Pipeline at iter T (band-row k <-> abs gy = gy0 + k - 3):
//   C(T):  consume pend (u row T) -> Du/Su/ucen[T%3]
//          Du[c]=u[c+3]-u[c+1], Su[c]=u[c+1]+2u[c+2]+u[c+3]
//   L'(T): load u band-row T+1 -> pend (abs gy0+T-2)
//   UX(T): ux row T-1 -> xw/yw[(T-1)%3]: ux=Du(t)+2Du(m)+Du(b), uy=Su(b)-Su(t)
//   PQ(T): P,Q row T-2 -> pre-reduced dP/eQ[(T-2)%3]
//   OUT(T): out row T-3 = u + (dP[r-1]+2dP[r]+dP[r+1]) + (eQ[r+1]-eQ[r-1])
// Block: 256 threads = 2 bands x 128 strips (4 cols each). Grid y = H/(2*HB).

#define HB   8
#define NROW (HB + 6)   // 14 active pipeline iterations
#define NT   256

typedef float f4v __attribute__((ext_vector_type(4)));

#define STEP(TT, S0, S1, S2) do {                                              \
    const int Tt = (TT);                                                       \
    const float ur0 = ucen[S0][0], ur1 = ucen[S0][1],                          \
                ur2 = ucen[S0][2], ur3 = ucen[S0][3];                          \
    if (Tt < NROW) {                                                           \
        /* ---- C(Tt): consume pend (u row Tt) -> Du/Su/ucen[S0] ---- */       \
        float* du = Du[S0]; float* su = Su[S0];                                \
        _Pragma("unroll") for (int c = 0; c < 8; ++c) {                        \
            du[c] = pend[c+3] - pend[c+1];                                     \
            su[c] = pend[c+1] + 2.f*pend[c+2] + pend[c+3];                     \
        }                                                                      \
        ucen[S0][0] = pend[4]; ucen[S0][1] = pend[5];                          \
        ucen[S0][2] = pend[6]; ucen[S0][3] = pend[7];                          \
    }                                                                          \
    if (Tt + 1 < NROW) {                                                       \
        /* ---- L'(Tt): load u band-row Tt+1 -> pend (abs gy=gy0+Tt-2) ---- */ \
        const int gy = gy0 + Tt - 2;                                           \
        if ((unsigned)gy < (unsigned)H) {                                      \
            const float* row = uc + (long)gy * W;                              \
            *(float4*)&pend[0] = *(const float4*)(row + ca);                   \
            *(float4*)&pend[4] = *(const float4*)(row + c0);                   \
            *(float4*)&pend[8] = *(const float4*)(row + cc);                   \
        } else {                                                               \
            _Pragma("unroll") for (int i = 0; i < 12; ++i) pend[i] = 0.f;      \
        }                                                                      \
    }                                                                          \
    if (Tt >= 2 && Tt < NROW) {                                                \
        /* ---- UX(Tt): ux/uy band-row Tt-1 (abs gy=gy0+Tt-4) -> slot S2 ---- */ \
        float* xr = xw[S2]; float* yr = yw[S2];                                \
        const int gy = gy0 + Tt - 4;                                           \
        if ((unsigned)gy < (unsigned)H) {                                      \
            _Pragma("unroll") for (int c = 0; c < 8; ++c) {                    \
                xr[c] = Du[S1][c] + 2.f*Du[S2][c] + Du[S0][c];                 \
                yr[c] = Su[S0][c] - Su[S1][c];                                 \
            }                                                                  \
        } else {                                                               \
            _Pragma("unroll") for (int c = 0; c < 8; ++c) { xr[c]=0.f; yr[c]=0.f; } \
        }                                                                      \
    }                                                                          \
    if (Tt >= 4 && Tt < NROW) {                                                \
        /* ---- PQ(Tt): P band-row Tt-2 (abs gy=gy0+Tt-5) -> dP/eQ[S1] ---- */ \
        float* dp = dP[S1]; float* eq = eQ[S1];                                \
        const int gy = gy0 + Tt - 5;                                           \
        if ((unsigned)gy < (unsigned)H) {                                      \
            const float* xt = xw[S0];  /* ux row Tt-3 */                       \
            const float* xm = xw[S1];  /* ux row Tt-2 */                       \
            const float* xb = xw[S2];  /* ux row Tt-1 */                       \
            const float* yt = yw[S0];                                          \
            const float* ym = yw[S1];                                          \
            const float* yb = yw[S2];                                          \
            float P[6], Q[6];                                                  \
            _Pragma("unroll") for (int c = 0; c < 6; ++c) {                    \
                const float xc = xm[c+1], yc = ym[c+1];                        \
                const float uxx = (xt[c+2]-xt[c]) + 2.f*(xm[c+2]-xm[c])        \
                                + (xb[c+2]-xb[c]);                             \
                const float uxy = (xb[c] + 2.f*xb[c+1] + xb[c+2])              \
                                - (xt[c] + 2.f*xt[c+1] + xt[c+2]);             \
                const float uyy = (yb[c] + 2.f*yb[c+1] + yb[c+2])              \
                                - (yt[c] + 2.f*yt[c+1] + yt[c+2]);             \
                const float den = 1.f + xc*xc + yc*yc;                         \
                const float Gv = (uxx*uyy - uxy*uxy)                           \
                               * __builtin_amdgcn_rcpf(den*den + 1e-6f);       \
                const float phi = __expf(-fabsf(Gv));                          \
                P[c] = phi * xc;                                               \
                Q[c] = phi * yc;                                               \
            }                                                                  \
            dp[0] = P[2]-P[0]; dp[1] = P[3]-P[1];                              \
            dp[2] = P[4]-P[2]; dp[3] = P[5]-P[3];                              \
            eq[0] = Q[0]+2.f*Q[1]+Q[2]; eq[1] = Q[1]+2.f*Q[2]+Q[3];            \
            eq[2] = Q[2]+2.f*Q[3]+Q[4]; eq[3] = Q[3]+2.f*Q[4]+Q[5];            \
        } else {                                                               \
            _Pragma("unroll") for (int c = 0; c < 4; ++c) { dp[c]=0.f; eq[c]=0.f; } \
        }                                                                      \
    }                                                                          \
    if (Tt >= 6 && Tt < NROW) {                                                \
        /* ---- OUT(Tt): out band-row Tt-3, abs gy = gy0+Tt-6 (in-domain) ---- */ \
        f4v o;                                                                 \
        o.x = ur0 + (dP[S2][0] + 2.f*dP[S0][0] + dP[S1][0])                    \
                  + (eQ[S1][0] - eQ[S2][0]);                                   \
        o.y = ur1 + (dP[S2][1] + 2.f*dP[S0][1] + dP[S1][1])                    \
                  + (eQ[S1][1] - eQ[S2][1]);                                   \
        o.z = ur2 + (dP[S2][2] + 2.f*dP[S0][2] + dP[S1][2])                    \
                  + (eQ[S1][2] - eQ[S2][2]);                                   \
        o.w = ur3 + (dP[S2][3] + 2.f*dP[S0][3] + dP[S1][3])                    \
                  + (eQ[S1][3] - eQ[S2][3]);                                   \
        __builtin_nontemporal_store(o, (f4v*)(oc + (long)(gy0 + Tt - 6) * W + c0)); \
    }                                                                          \
} while (0)

__global__ __launch_bounds__(NT) void gcdd_sweep(
    const float* __restrict__ u, float* __restrict__ out, int H, int W)
{
    const int tid   = threadIdx.x;
    const int strip = tid & 127;          // 128 strips x 4 cols = W = 512
    const int band  = tid >> 7;           // 2 bands per block (wave-uniform)
    const int c0    = strip * 4;
    const int gy0   = (blockIdx.y * 2 + band) * HB;
    const long chan = blockIdx.z;
    const float* __restrict__ uc = u + chan * (long)H * W;
    float* __restrict__ oc = out + chan * (long)H * W;

    // Clamped side-load cols: edge strips read garbage there; the affected
    // out cols {0,1,2, W-3,W-2,W-1} are rewritten by gcdd_fix.
    const int ca = (c0 - 4 < 0) ? 0 : (c0 - 4);
    const int cc = (c0 + 4 > W - 4) ? (W - 4) : (c0 + 4);

    float pend[12];
    float Du[3][8], Su[3][8];
    float ucen[3][4] = {};
    float xw[3][8], yw[3][8];
    float dP[3][4], eQ[3][4];

    // ---- Prologue: load band-row 0 (abs gy = gy0-3) into pend ----
    {
        const int gy = gy0 - 3;
        if ((unsigned)gy < (unsigned)H) {
            const float* row = uc + (long)gy * W;
            *(float4*)&pend[0] = *(const float4*)(row + ca);
            *(float4*)&pend[4] = *(const float4*)(row + c0);
            *(float4*)&pend[8] = *(const float4*)(row + cc);
        } else {
            #pragma unroll
            for (int i = 0; i < 12; ++i) pend[i] = 0.f;
        }
    }

    // 15 iterations (14 active), 3x-unrolled: all slot indices literal.
    for (int t = 0; t < NROW + 1; t += 3) {
        STEP(t + 0, 0, 1, 2);
        STEP(t + 1, 1, 2, 0);
        STEP(t + 2, 2, 0, 1);
    }
}

// Fixup: fully-masked per-pixel cascade for out cols {0,1,2, W-3,W-2,W-1}.
// 6*H*CH threads; u working set is ~12 cols -> L2-resident; runs in a few us.
__global__ __launch_bounds__(256) void gcdd_fix(
    const float* __restrict__ u, float* __restrict__ out, int H, int W, int CH)
{
    const int idx = blockIdx.x * 256 + threadIdx.x;
    if (idx >= 6 * H * CH) return;
    const int gy = idx % H;
    const int t  = idx / H;
    const int cs = t % 6;
    const int ch = t / 6;
    const int gx = (cs < 3) ? cs : (W - 6 + cs);
    const float* __restrict__ uc = u + (long)ch * H * W;
    float* __restrict__ oc = out + (long)ch * H * W;

    float uv[7][7];
    #pragma unroll
    for (int r = 0; r < 7; ++r) {
        const int ry = gy - 3 + r;
        const bool ri = (unsigned)ry < (unsigned)H;
        const int ryc = ri ? ry : 0;
        #pragma unroll
        for (int c = 0; c < 7; ++c) {
            const int cx = gx - 3 + c;
            const bool ci = (unsigned)cx < (unsigned)W;
            const int cxc = ci ? cx : 0;
            const float v = uc[(long)ryc * W + cxc];
            uv[r][c] = (ri & ci) ? v : 0.f;
        }
    }
    float ux[5][5], uy[5][5];
    #pragma unroll
    for (int r = 0; r < 5; ++r) {
        const bool ri = (unsigned)(gy - 2 + r) < (unsigned)H;
        #pragma unroll
        for (int c = 0; c < 5; ++c) {
            const bool in = ri & ((unsigned)(gx - 2 + c) < (unsigned)W);
            const float A = uv[r][c],   B = uv[r][c+1],   C = uv[r][c+2];
            const float D = uv[r+1][c],                   E = uv[r+1][c+2];
            const float F = uv[r+2][c], G = uv[r+2][c+1], Hh = uv[r+2][c+2];
            const float x = (C - A) + 2.f*(E - D) + (Hh - F);
            const float y = (F + 2.f*G + Hh) - (A + 2.f*B + C);
            ux[r][c] = in ? x : 0.f;
            uy[r][c] = in ? y : 0.f;
        }
    }
    float P[3][3], Q[3][3];
    #pragma unroll
    for (int r = 0; r < 3; ++r) {
        const bool ri = (unsigned)(gy - 1 + r) < (unsigned)H;
        #pragma unroll
        for (int c = 0; c < 3; ++c) {
            const bool in = ri & ((unsigned)(gx - 1 + c) < (unsigned)W);
            const float xc = ux[r+1][c+1], yc = uy[r+1][c+1];
            const float uxx = (ux[r][c+2]-ux[r][c]) + 2.f*(ux[r+1][c+2]-ux[r+1][c])
                            + (ux[r+2][c+2]-ux[r+2][c]);
            const float uxy = (ux[r+2][c] + 2.f*ux[r+2][c+1] + ux[r+2][c+2])
                            - (ux[r][c]   + 2.f*ux[r][c+1]   + ux[r][c+2]);
            const float uyy = (uy[r+2][c] + 2.f*uy[r+2][c+1] + uy[r+2][c+2])
                            - (uy[r][c]   + 2.f*uy[r][c+1]   + uy[r][c+2]);
            const float den = 1.f + xc*xc + yc*yc;
            const float Gv = (uxx*uyy - uxy*uxy)
                           * __builtin_amdgcn_rcpf(den*den + 1e-6f);
            const float phi = __expf(-fabsf(Gv));
            P[r][c] = in ? phi * xc : 0.f;
            Q[r][c] = in ? phi * yc : 0.f;
        }
    }
    const float divx = (P[0][2]-P[0][0]) + 2.f*(P[1][2]-P[1][0]) + (P[2][2]-P[2][0]);
    const float divy = (Q[2][0] + 2.f*Q[2][1] + Q[2][2])
                     - (Q[0][0] + 2.f*Q[0][1] + Q[0][2]);
    oc[(long)gy * W + gx] = uv[3][3] + divx + divy;
}

extern "C" void kernel_launch(void* const* d_in, const int* in_sizes, int n_in,
                              void* d_out, int out_size, void* d_ws, size_t ws_size,
                              hipStream_t stream) {
    const float* u = (const float*)d_in[0];
    float* out = (float*)d_out;

    const int H = 512, W = 512;
    const int channels = in_sizes[0] / (H * W);  // B*C = 48

    dim3 grid(1, H / (2 * HB), channels);        // 1 x 32 x 48 = 1536 blocks
    gcdd_sweep<<<grid, dim3(NT), 0, stream>>>(u, out, H, W);

    const int nfix = 6 * H * channels;           // 147,456
    gcdd_fix<<<(nfix + 255) / 256, 256, 0, stream>>>(u, out, H, W, channels);
}